// Round 9
// baseline (363.919 us; speedup 1.0000x reference)
//
#include <hip/hip_runtime.h>

typedef float f32x4 __attribute__((ext_vector_type(4)));
typedef short short8 __attribute__((ext_vector_type(8)));
typedef short s16x4 __attribute__((ext_vector_type(4)));

#define MFMA16(a, b, c) __builtin_amdgcn_mfma_f32_16x16x32_bf16((a), (b), (c), 0, 0, 0)

#define T_ 256
#define B_ 1024
#define H_ 128
#define TB_ 262144
#define BH_ 131072
#define LOG2PI_F 1.8378770664093453f
#define LN2_F 0.6931471805599453f
#define LOG2E_F 1.4426950408889634f

__device__ inline short f2bf(float f) {
    unsigned u = __builtin_bit_cast(unsigned, f);
    u += 0x7fffu + ((u >> 16) & 1u);
    return (short)(u >> 16);
}
__device__ inline float fexp(float x) { return __builtin_amdgcn_exp2f(x * LOG2E_F); }
__device__ inline float fsigm(float x) { return __builtin_amdgcn_rcpf(1.f + fexp(-x)); }
__device__ inline float ftanh(float x) { return 1.f - 2.f * __builtin_amdgcn_rcpf(fexp(2.f * x) + 1.f); }

__device__ inline short8 pack8(float4 u0, float4 u1) {
    short8 p;
    p[0] = f2bf(u0.x); p[1] = f2bf(u0.y); p[2] = f2bf(u0.z); p[3] = f2bf(u0.w);
    p[4] = f2bf(u1.x); p[5] = f2bf(u1.y); p[6] = f2bf(u1.z); p[7] = f2bf(u1.w);
    return p;
}

__device__ __forceinline__ size_t x2gidx(int G, int toff, int j, int dim, int blk) {
    int tt = G * 4 + toff; tt = tt <= 255 ? tt : 255;
    return (((size_t)tt * 256 + blk) * 4 + j) * 128 + dim;
}

// one fused head (value + action-mean) for timestep th, from the hring slot
__device__ __forceinline__ void do_head(
    const short* hring, const f32x4* poolp, float biasH,
    int aoff, int kg, int l15, float* hd, int th)
{
    const short* hr = &hring[(th & 15) * 640];
    short8 ah0 = *(const short8*)&hr[aoff + 0 * 32 + kg * 8];
    short8 ah1 = *(const short8*)&hr[aoff + 1 * 32 + kg * 8];
    short8 ah2 = *(const short8*)&hr[aoff + 2 * 32 + kg * 8];
    short8 ah3 = *(const short8*)&hr[aoff + 3 * 32 + kg * 8];
    f32x4 aH = {biasH, biasH, biasH, biasH};
    aH = MFMA16(ah0, __builtin_bit_cast(short8, poolp[8]), aH);
    aH = MFMA16(ah1, __builtin_bit_cast(short8, poolp[9]), aH);
    aH = MFMA16(ah2, __builtin_bit_cast(short8, poolp[10]), aH);
    aH = MFMA16(ah3, __builtin_bit_cast(short8, poolp[11]), aH);
    if (l15 < 9) hd[(th * 4 + kg) * 12 + l15] = aH[0];
}

// ---------------- EX: encoder only (obs -> x2), 64-row tiles; weights converted in-reg ----------------
__global__ __launch_bounds__(512, 4) void ex_kernel(
    const float* __restrict__ obs, const float* __restrict__ eb1,
    const float* __restrict__ eb2,
    const float* __restrict__ w1f, const float* __restrict__ w2f,
    short* __restrict__ x2p)
{
    __shared__ __align__(16) short xtA[64 * 128];
    __shared__ __align__(16) short xtB[64 * 128];
    __shared__ __align__(16) short xtC[64 * 128];
    const int tid = threadIdx.x;
    const int l = tid & 63, w = tid >> 6;
    const int l15 = l & 15, kg = l >> 4;
    const int srow = tid >> 3, sln = tid & 7;
    const int ssw = (srow & 7) << 3;

    short8 fw1[4], fw2[4];
#pragma unroll
    for (int kk = 0; kk < 4; ++kk) {
        const float* s1 = w1f + (w * 16 + l15) * 128 + kk * 32 + 8 * kg;
        const float* s2 = w2f + (w * 16 + l15) * 128 + kk * 32 + 8 * kg;
        fw1[kk] = pack8(*(const float4*)s1, *(const float4*)(s1 + 4));
        fw2[kk] = pack8(*(const float4*)s2, *(const float4*)(s2 + 4));
        asm volatile("" : "+v"(fw1[kk]), "+v"(fw2[kk]));
    }
    const float bb1 = eb1[w * 16 + l15], bb2 = eb2[w * 16 + l15];

    const int NT = 8;
    const int t0 = blockIdx.x * NT;

    {
        const float* src = obs + ((size_t)t0 * 64 + srow) * 128 + sln * 16;
#pragma unroll
        for (int ii = 0; ii < 2; ++ii) {
            float4 v0 = *(const float4*)(src + ii * 8);
            float4 v1 = *(const float4*)(src + ii * 8 + 4);
            *(short8*)(xtA + srow * 128 + ((sln * 16 + ii * 8) ^ ssw)) = pack8(v0, v1);
        }
    }
    __syncthreads();

    for (int i = 0; i < NT; ++i) {
        const int tile = t0 + i;
        short* bufO = (i & 1) ? xtB : xtA;
        short* bufN = (i & 1) ? xtA : xtB;

        float4 pf[4];
        {
            const int tn = (i + 1 < NT) ? tile + 1 : tile;
            const float* src = obs + ((size_t)tn * 64 + srow) * 128 + sln * 16;
#pragma unroll
            for (int ii = 0; ii < 4; ++ii) pf[ii] = *(const float4*)(src + ii * 4);
        }

#pragma unroll
        for (int mf = 0; mf < 4; ++mf) {
            const int ra = mf * 16 + l15, swa = (ra & 7) << 3;
            short8 a[4];
#pragma unroll
            for (int kk = 0; kk < 4; ++kk)
                a[kk] = *(const short8*)&bufO[ra * 128 + ((kk * 32 + 8 * kg) ^ swa)];
            f32x4 acc = {bb1, bb1, bb1, bb1};
#pragma unroll
            for (int kk = 0; kk < 4; ++kk) acc = MFMA16(a[kk], fw1[kk], acc);
#pragma unroll
            for (int j = 0; j < 4; ++j) {
                int rw = mf * 16 + kg * 4 + j;
                xtC[rw * 128 + ((w * 16 + l15) ^ ((rw & 7) << 3))] = f2bf(ftanh(acc[j]));
            }
        }
        __syncthreads();

        const int t = (tile * 64) >> 10;
        const int b_base = (tile * 64) & 1023;
#pragma unroll
        for (int mf = 0; mf < 4; ++mf) {
            const int ra = mf * 16 + l15, swa = (ra & 7) << 3;
            short8 a[4];
#pragma unroll
            for (int kk = 0; kk < 4; ++kk)
                a[kk] = *(const short8*)&xtC[ra * 128 + ((kk * 32 + 8 * kg) ^ swa)];
            f32x4 acc = {bb2, bb2, bb2, bb2};
#pragma unroll
            for (int kk = 0; kk < 4; ++kk) acc = MFMA16(a[kk], fw2[kk], acc);
#pragma unroll
            for (int j = 0; j < 4; ++j) {
                int b = b_base + mf * 16 + kg * 4 + j;
                size_t idx = (((size_t)t * 256 + (b >> 2)) * 4 + (b & 3)) * 128 + w * 16 + l15;
                x2p[idx] = f2bf(ftanh(acc[j]));
            }
        }
#pragma unroll
        for (int ii = 0; ii < 2; ++ii) {
            *(short8*)(bufN + srow * 128 + ((sln * 16 + ii * 8) ^ ssw)) =
                pack8(pf[ii * 2], pf[ii * 2 + 1]);
        }
        __syncthreads();
    }
}

// ---------------- R: LSTM with producer/consumer wave split ----------------
// 8 waves: G-waves 0-3 (gate GEMM: wave w = gate w, all 128 d, 32 MFMA/step, bh in C-init,
// results -> gbuf LDS) and E-waves 4-7 (phase1: x-chain MFMA for next group + staging;
// phase2: cell epilogue for 2 d-cells/lane from gbuf + reg xg, writes hbuf/hring).
// 2 barriers/step. Register economy: wB[32] short8 shared (whh frags on G / wih frags on E);
// f32x4 pool[16]: E = xgA(0..7)+xgB(8..15); G = head frags (8..11) + bh (12..13).
__global__ __launch_bounds__(512) void lstm_kernel(
    const short* __restrict__ x2p, const float* __restrict__ whh,
    const float* __restrict__ wih,
    const float* __restrict__ h0, const float* __restrict__ c0,
    const float* __restrict__ bhh, const float* __restrict__ bih,
    const float* __restrict__ dones,
    const float* __restrict__ amw, const float* __restrict__ crw,
    const float* __restrict__ amb, const float* __restrict__ crb,
    const float* __restrict__ lstd, const float* __restrict__ actions,
    float* __restrict__ out)
{
    __shared__ __align__(16) short hbuf[2][4 * 160];   // masked h dbuf
    __shared__ __align__(16) short hring[16 * 640];    // unmasked h2 ring
    __shared__ __align__(16) short x2b[2][16 * 160];   // x2 group slots (XOR-swizzled)
    __shared__ __align__(16) float gbuf[2176];         // h-gates+bh: [(s*4+b)*136 + d]
    __shared__ float dlds[1028];
    __shared__ float hd[1024 * 12];
    const int tid = threadIdx.x;
    const int l = tid & 63, w = tid >> 6;
    const int l15 = l & 15, kg = l >> 4;
    const int b0 = blockIdx.x * 4;
    const int blk = blockIdx.x;
    const int xsw = (l15 & 7) << 3;
    const bool isG = (w < 4);
    const int e = w & 3;
    const int d0 = e * 32 + l15, d1 = d0 + 16;         // E cells
    const int aoff = (l15 >> 2) * 160;                 // quad-replicated A rows

    short8 wB[32];
    f32x4 pool[16];
    float biasH = 0.f;
    s16x4 xpfa, xpfb;
    float c0_ = 0.f, c1_ = 0.f, h0_ = 0.f, h1_ = 0.f, mreg = 1.f;

    // staging tuples (used by G only)
    const int sa = tid & 255;
    const int ta_toff = sa >> 7, ta_j = (sa >> 5) & 3, ta_dim = (sa & 31) * 4;
    const int ra_ = ta_j * 4 + ta_toff;
    const int xrowA = ra_ * 160 + (ta_dim ^ ((ra_ & 7) << 3));
    const int sb = (tid & 255) + 256;
    const int tb_toff = sb >> 7, tb_j = (sb >> 5) & 3, tb_dim = (sb & 31) * 4;
    const int rb_ = tb_j * 4 + tb_toff;
    const int xrowB = rb_ * 160 + (tb_dim ^ ((rb_ & 7) << 3));

    if (isG) {
        // whh B-frags: wave w = gate w, col-tiles ct 0..7
#pragma unroll
        for (int ct = 0; ct < 8; ++ct)
#pragma unroll
            for (int kk = 0; kk < 4; ++kk) {
                const float* s0 = whh + ((w * 128 + ct * 16 + l15) * 128 + kk * 32 + 8 * kg);
                wB[ct * 4 + kk] = pack8(*(const float4*)s0, *(const float4*)(s0 + 4));
            }
        // head B-frags into pool[8..11]
#pragma unroll
        for (int kk = 0; kk < 4; ++kk) {
            short8 hq;
            if (l15 == 0) {
                const float* s0 = crw + kk * 32 + 8 * kg;
                hq = pack8(*(const float4*)s0, *(const float4*)(s0 + 4));
            } else if (l15 <= 8) {
                const float* s0 = amw + (l15 - 1) * 128 + kk * 32 + 8 * kg;
                hq = pack8(*(const float4*)s0, *(const float4*)(s0 + 4));
            } else {
                hq = short8{0, 0, 0, 0, 0, 0, 0, 0};
            }
            pool[8 + kk] = __builtin_bit_cast(f32x4, hq);
        }
        biasH = (l15 == 0) ? crb[0] : (l15 <= 8 ? amb[l15 - 1] : 0.f);
        // bh into pool[12..13]: bh[ct] for cols w*128 + ct*16 + l15
        f32x4 bA, bB;
#pragma unroll
        for (int ct = 0; ct < 4; ++ct) {
            bA[ct] = bhh[w * 128 + ct * 16 + l15] + bih[w * 128 + ct * 16 + l15];
            bB[ct] = bhh[w * 128 + (ct + 4) * 16 + l15] + bih[w * 128 + (ct + 4) * 16 + l15];
        }
        pool[12] = bA; pool[13] = bB;
    } else {
        // wih B-frags: gate s, 2 col-tiles (d0-tile, d1-tile)
#pragma unroll
        for (int s = 0; s < 4; ++s)
#pragma unroll
            for (int ct2 = 0; ct2 < 2; ++ct2)
#pragma unroll
                for (int kk = 0; kk < 4; ++kk) {
                    const float* s0 = wih + ((s * 128 + e * 32 + ct2 * 16 + l15) * 128 + kk * 32 + 8 * kg);
                    wB[(s * 2 + ct2) * 4 + kk] = pack8(*(const float4*)s0, *(const float4*)(s0 + 4));
                }
        h0_ = h0[(b0 + kg) * 128 + d0]; h1_ = h0[(b0 + kg) * 128 + d1];
        c0_ = c0[(b0 + kg) * 128 + d0]; c1_ = c0[(b0 + kg) * 128 + d1];
    }
#pragma unroll
    for (int i = 0; i < 32; ++i) asm volatile("" : "+v"(wB[i]));

    for (int i = tid; i < 1028; i += 512) {
        int t = i >> 2, jj = i & 3;
        dlds[i] = (t < 256) ? 1.f - dones[t * 1024 + b0 + jj] : 1.f;
    }

    // staging prologue (G threads): groups 0,1 -> x2b[0],[1]; prefetch group 2
    if (isG) {
        s16x4 va0 = *(const s16x4*)(x2p + x2gidx(0, ta_toff, ta_j, ta_dim, blk));
        s16x4 vb0 = *(const s16x4*)(x2p + x2gidx(0, tb_toff, tb_j, tb_dim, blk));
        s16x4 va1 = *(const s16x4*)(x2p + x2gidx(1, ta_toff, ta_j, ta_dim, blk));
        s16x4 vb1 = *(const s16x4*)(x2p + x2gidx(1, tb_toff, tb_j, tb_dim, blk));
        *(s16x4*)&x2b[0][xrowA] = va0;
        *(s16x4*)&x2b[0][xrowB] = vb0;
        *(s16x4*)&x2b[1][xrowA] = va1;
        *(s16x4*)&x2b[1][xrowB] = vb1;
        xpfa = *(const s16x4*)(x2p + x2gidx(2, ta_toff, ta_j, ta_dim, blk));
        xpfb = *(const s16x4*)(x2p + x2gidx(2, tb_toff, tb_j, tb_dim, blk));
    }
    asm volatile("s_waitcnt lgkmcnt(0)" ::: "memory");
    __syncthreads();   // x2b[0],[1], dlds ready

    // E prologue: xgA (group 0) from x2b[0], C-in 0 (bh lives in gbuf now); init hbuf[0]
    if (!isG) {
        short8 ax[4];
#pragma unroll
        for (int kk = 0; kk < 4; ++kk)
            ax[kk] = *(const short8*)&x2b[0][l15 * 160 + ((kk * 32 + kg * 8) ^ xsw)];
#pragma unroll
        for (int s = 0; s < 4; ++s)
#pragma unroll
            for (int ct2 = 0; ct2 < 2; ++ct2) {
                f32x4 accX = {0.f, 0.f, 0.f, 0.f};
#pragma unroll
                for (int kk = 0; kk < 4; ++kk)
                    accX = MFMA16(ax[kk], wB[(s * 2 + ct2) * 4 + kk], accX);
                pool[s * 2 + ct2] = accX;
            }
        mreg = dlds[kg];
        hbuf[0][kg * 160 + d0] = f2bf(h0_ * mreg);
        hbuf[0][kg * 160 + d1] = f2bf(h1_ * mreg);
    }
    asm volatile("s_waitcnt lgkmcnt(0)" ::: "memory");
    __syncthreads();   // hbuf[0] ready

    // XGC/XGN are pool base offsets (0 = xgA, 8 = xgB)
#define STEP(t, hb, i_s, XGC, XGN, x2R, x2W, DO_T3, GNEXT, DO_HEAD)                        \
    {                                                                                      \
        if (isG) {                                                                         \
            short8 a[4];                                                                   \
            _Pragma("unroll")                                                              \
            for (int kk = 0; kk < 4; ++kk)                                                 \
                a[kk] = *(const short8*)&hbuf[hb][aoff + kk * 32 + kg * 8];                \
            f32x4 acc[4];                                                                  \
            _Pragma("unroll")                                                              \
            for (int ct = 0; ct < 4; ++ct) {                                               \
                float bv = pool[12][ct];                                                   \
                f32x4 ini = {bv, bv, bv, bv};                                              \
                acc[ct] = ini;                                                             \
            }                                                                              \
            _Pragma("unroll")                                                              \
            for (int kk = 0; kk < 4; ++kk)                                                 \
                _Pragma("unroll")                                                          \
                for (int ct = 0; ct < 4; ++ct)                                             \
                    acc[ct] = MFMA16(a[kk], wB[ct * 4 + kk], acc[ct]);                     \
            _Pragma("unroll")                                                              \
            for (int ct = 0; ct < 4; ++ct)                                                 \
                gbuf[(w * 4 + kg) * 136 + ct * 16 + l15] = acc[ct][0];                     \
            _Pragma("unroll")                                                              \
            for (int ct = 0; ct < 4; ++ct) {                                               \
                float bv = pool[13][ct];                                                   \
                f32x4 ini = {bv, bv, bv, bv};                                              \
                acc[ct] = ini;                                                             \
            }                                                                              \
            _Pragma("unroll")                                                              \
            for (int kk = 0; kk < 4; ++kk)                                                 \
                _Pragma("unroll")                                                          \
                for (int ct = 0; ct < 4; ++ct)                                             \
                    acc[ct] = MFMA16(a[kk], wB[(ct + 4) * 4 + kk], acc[ct]);               \
            _Pragma("unroll")                                                              \
            for (int ct = 0; ct < 4; ++ct)                                                 \
                gbuf[(w * 4 + kg) * 136 + (ct + 4) * 16 + l15] = acc[ct][0];               \
            if (DO_T3) {                                                                   \
                *(s16x4*)&x2W[xrowA] = xpfa;                                               \
                *(s16x4*)&x2W[xrowB] = xpfb;                                               \
                xpfa = *(const s16x4*)(x2p + x2gidx(GNEXT, ta_toff, ta_j, ta_dim, blk));   \
                xpfb = *(const s16x4*)(x2p + x2gidx(GNEXT, tb_toff, tb_j, tb_dim, blk));   \
            }                                                                              \
        } else {                                                                           \
            short8 ax[4];                                                                  \
            _Pragma("unroll")                                                              \
            for (int kk = 0; kk < 4; ++kk)                                                 \
                ax[kk] = *(const short8*)&x2R[l15 * 160 + ((kk * 32 + kg * 8) ^ xsw)];     \
            f32x4 xt0 = {0.f, 0.f, 0.f, 0.f};                                              \
            f32x4 xt1 = {0.f, 0.f, 0.f, 0.f};                                              \
            _Pragma("unroll")                                                              \
            for (int kk = 0; kk < 4; ++kk) {                                               \
                xt0 = MFMA16(ax[kk], wB[((i_s) * 2 + 0) * 4 + kk], xt0);                   \
                xt1 = MFMA16(ax[kk], wB[((i_s) * 2 + 1) * 4 + kk], xt1);                   \
            }                                                                              \
            pool[(XGN) + (i_s) * 2 + 0] = xt0;                                             \
            pool[(XGN) + (i_s) * 2 + 1] = xt1;                                             \
        }                                                                                  \
        asm volatile("s_waitcnt lgkmcnt(0)" ::: "memory");                                 \
        __builtin_amdgcn_s_barrier();                                                      \
        asm volatile("" ::: "memory");                                                     \
        if (!isG) {                                                                        \
            float mn = dlds[((t) + 1) * 4 + kg];                                           \
            float gi0 = gbuf[(0 * 4 + kg) * 136 + d0] + pool[(XGC) + 0][i_s];              \
            float gf0 = gbuf[(1 * 4 + kg) * 136 + d0] + pool[(XGC) + 2][i_s];              \
            float gg0 = gbuf[(2 * 4 + kg) * 136 + d0] + pool[(XGC) + 4][i_s];              \
            float go0 = gbuf[(3 * 4 + kg) * 136 + d0] + pool[(XGC) + 6][i_s];              \
            float gi1 = gbuf[(0 * 4 + kg) * 136 + d1] + pool[(XGC) + 1][i_s];              \
            float gf1 = gbuf[(1 * 4 + kg) * 136 + d1] + pool[(XGC) + 3][i_s];              \
            float gg1 = gbuf[(2 * 4 + kg) * 136 + d1] + pool[(XGC) + 5][i_s];              \
            float go1 = gbuf[(3 * 4 + kg) * 136 + d1] + pool[(XGC) + 7][i_s];              \
            c0_ = fsigm(gf0) * (c0_ * mreg) + fsigm(gi0) * ftanh(gg0);                     \
            float h20 = fsigm(go0) * ftanh(c0_);                                           \
            c1_ = fsigm(gf1) * (c1_ * mreg) + fsigm(gi1) * ftanh(gg1);                     \
            float h21 = fsigm(go1) * ftanh(c1_);                                           \
            hbuf[(hb) ^ 1][kg * 160 + d0] = f2bf(h20 * mn);                                \
            hbuf[(hb) ^ 1][kg * 160 + d1] = f2bf(h21 * mn);                                \
            hring[((t) & 15) * 640 + kg * 160 + d0] = f2bf(h20);                           \
            hring[((t) & 15) * 640 + kg * 160 + d1] = f2bf(h21);                           \
            h0_ = h20; h1_ = h21; mreg = mn;                                               \
        } else if (DO_HEAD) {                                                              \
            do_head(hring, pool, biasH, aoff, kg, l15, hd, (t) - 8 + w * 2);               \
            do_head(hring, pool, biasH, aoff, kg, l15, hd, (t) - 8 + w * 2 + 1);           \
        }                                                                                  \
        asm volatile("s_waitcnt lgkmcnt(0)" ::: "memory");                                 \
        __builtin_amdgcn_s_barrier();                                                      \
        asm volatile("" ::: "memory");                                                     \
    }

    for (int g = 0; g < 64; g += 2) {
        {   // even group g: consume xgA (pool 0), produce xgB (pool 8) from x2b[1]
            const int tb = g * 4;
            const short* x2R = &x2b[1][0];
            short* x2W = &x2b[0][0];
            STEP(tb + 0, 0, 0, 0, 8, x2R, x2W, 0, 0, (g > 0));
            STEP(tb + 1, 1, 1, 0, 8, x2R, x2W, 0, 0, 0);
            STEP(tb + 2, 0, 2, 0, 8, x2R, x2W, 0, 0, 0);
            STEP(tb + 3, 1, 3, 0, 8, x2R, x2W, 1, (g + 3), 0);
        }
        {   // odd group g+1: consume xgB (pool 8), produce xgA (pool 0) from x2b[0]
            const int tb = (g + 1) * 4;
            const short* x2R = &x2b[0][0];
            short* x2W = &x2b[1][0];
            STEP(tb + 0, 0, 0, 8, 0, x2R, x2W, 0, 0, 0);
            STEP(tb + 1, 1, 1, 8, 0, x2R, x2W, 0, 0, 0);
            STEP(tb + 2, 0, 2, 8, 0, x2R, x2W, 0, 0, 0);
            STEP(tb + 3, 1, 3, 8, 0, x2R, x2W, 1, (g + 4), 0);
        }
    }
#undef STEP

    // tail: G-waves do final heads (t=248..255); E-waves write hT/cT
    if (isG) {
        do_head(hring, pool, biasH, aoff, kg, l15, hd, 248 + w * 2);
        do_head(hring, pool, biasH, aoff, kg, l15, hd, 248 + w * 2 + 1);
    } else {
        out[3 * TB_ + (b0 + kg) * 128 + d0] = h0_;
        out[3 * TB_ + (b0 + kg) * 128 + d1] = h1_;
        out[3 * TB_ + BH_ + (b0 + kg) * 128 + d0] = c0_;
        out[3 * TB_ + BH_ + (b0 + kg) * 128 + d1] = c1_;
    }

    // ---- fused logprob/entropy/value epilogue ----
    __syncthreads();
    for (int rr = tid; rr < 1024; rr += 512) {
        const int t = rr >> 2, bb = rr & 3;
        const float* hp = &hd[rr * 12];
        const float* ap = actions + ((size_t)t * 1024 + b0 + bb) * 8;
        float4 a0 = *(const float4*)(ap);
        float4 a1 = *(const float4*)(ap + 4);
        float act[8] = {a0.x, a0.y, a0.z, a0.w, a1.x, a1.y, a1.z, a1.w};
        float lp = 0.f, lj = 0.f, entS = 0.f;
#pragma unroll
        for (int ai = 0; ai < 8; ++ai) {
            float x = act[ai];
            float xc = fminf(fmaxf(x, -1.f + 1e-6f), 1.f - 1e-6f);
            float u = 0.5f * LN2_F *
                      (__builtin_amdgcn_logf(1.f + xc) - __builtin_amdgcn_logf(1.f - xc));
            float ls = lstd[ai];
            float z = (u - hp[1 + ai]) * fexp(-ls);
            lp += -0.5f * z * z - ls;
            lj += LN2_F * __builtin_amdgcn_logf(1.f - x * x + 1e-6f);
            entS += ls;
        }
        lp -= 8.f * 0.5f * LOG2PI_F;
        entS += 8.f * (0.5f + 0.5f * LOG2PI_F);
        const int r = t * 1024 + b0 + bb;
        out[r] = lp - lj;
        out[TB_ + r] = entS + lj;
        out[2 * TB_ + r] = hp[0];
    }
}

extern "C" void kernel_launch(void* const* d_in, const int* in_sizes, int n_in,
                              void* d_out, int out_size, void* d_ws, size_t ws_size,
                              hipStream_t stream) {
    const float* obs   = (const float*)d_in[0];
    const float* acts  = (const float*)d_in[1];
    const float* dones = (const float*)d_in[2];
    const float* h0    = (const float*)d_in[3];
    const float* c0    = (const float*)d_in[4];
    const float* w1    = (const float*)d_in[5];
    const float* b1    = (const float*)d_in[6];
    const float* w2    = (const float*)d_in[7];
    const float* b2    = (const float*)d_in[8];
    const float* wih   = (const float*)d_in[9];
    const float* whh   = (const float*)d_in[10];
    const float* bih   = (const float*)d_in[11];
    const float* bhh   = (const float*)d_in[12];
    const float* amw   = (const float*)d_in[13];
    const float* amb   = (const float*)d_in[14];
    const float* lstd  = (const float*)d_in[15];
    const float* crw   = (const float*)d_in[16];
    const float* crb   = (const float*)d_in[17];
    float* out = (float*)d_out;

    short* x2p = (short*)d_ws;               // 64 MB  [t][blk][j][dim] bf16
    if (ws_size < (size_t)67108864) return;

    hipLaunchKernelGGL(ex_kernel, dim3(512), dim3(512), 0, stream,
                       obs, b1, b2, w1, w2, x2p);
    hipLaunchKernelGGL(lstm_kernel, dim3(256), dim3(512), 0, stream,
                       x2p, whh, wih, h0, c0, bhh, bih, dones,
                       amw, crw, amb, crb, lstd, acts, out);
}

// Round 10
// 212.119 us; speedup vs baseline: 1.7156x; 1.7156x over previous
//
#include <hip/hip_runtime.h>

typedef float f32x4 __attribute__((ext_vector_type(4)));
typedef short short8 __attribute__((ext_vector_type(8)));
typedef short s16x4 __attribute__((ext_vector_type(4)));

#define MFMA16(a, b, c) __builtin_amdgcn_mfma_f32_16x16x32_bf16((a), (b), (c), 0, 0, 0)

#define T_ 256
#define B_ 1024
#define H_ 128
#define TB_ 262144
#define BH_ 131072
#define LOG2PI_F 1.8378770664093453f
#define LN2_F 0.6931471805599453f
#define LOG2E_F 1.4426950408889634f

__device__ inline short f2bf(float f) {
    unsigned u = __builtin_bit_cast(unsigned, f);
    u += 0x7fffu + ((u >> 16) & 1u);
    return (short)(u >> 16);
}
__device__ inline float fexp(float x) { return __builtin_amdgcn_exp2f(x * LOG2E_F); }
__device__ inline float fsigm(float x) { return __builtin_amdgcn_rcpf(1.f + fexp(-x)); }
__device__ inline float ftanh(float x) { return 1.f - 2.f * __builtin_amdgcn_rcpf(fexp(2.f * x) + 1.f); }

__device__ inline short8 pack8(float4 u0, float4 u1) {
    short8 p;
    p[0] = f2bf(u0.x); p[1] = f2bf(u0.y); p[2] = f2bf(u0.z); p[3] = f2bf(u0.w);
    p[4] = f2bf(u1.x); p[5] = f2bf(u1.y); p[6] = f2bf(u1.z); p[7] = f2bf(u1.w);
    return p;
}

// ---------------- EX: encoder only (obs -> x2), 64-row tiles; weights converted in-reg ----------------
// x2 layout: idx = ((t*256 + (b>>2))*4 + (b&3))*128 + dim   (1KB per (t, lstm-WG))
__global__ __launch_bounds__(512, 4) void ex_kernel(
    const float* __restrict__ obs, const float* __restrict__ eb1,
    const float* __restrict__ eb2,
    const float* __restrict__ w1f, const float* __restrict__ w2f,
    short* __restrict__ x2p)
{
    __shared__ __align__(16) short xtA[64 * 128];  // obs ping
    __shared__ __align__(16) short xtB[64 * 128];  // obs pong
    __shared__ __align__(16) short xtC[64 * 128];  // x1
    const int tid = threadIdx.x;
    const int l = tid & 63, w = tid >> 6;
    const int l15 = l & 15, kg = l >> 4;
    const int srow = tid >> 3, sln = tid & 7;      // staging: 8 threads/row
    const int ssw = (srow & 7) << 3;

    short8 fw1[4], fw2[4];
#pragma unroll
    for (int kk = 0; kk < 4; ++kk) {
        const float* s1 = w1f + (w * 16 + l15) * 128 + kk * 32 + 8 * kg;
        const float* s2 = w2f + (w * 16 + l15) * 128 + kk * 32 + 8 * kg;
        fw1[kk] = pack8(*(const float4*)s1, *(const float4*)(s1 + 4));
        fw2[kk] = pack8(*(const float4*)s2, *(const float4*)(s2 + 4));
        asm volatile("" : "+v"(fw1[kk]), "+v"(fw2[kk]));
    }
    const float bb1 = eb1[w * 16 + l15], bb2 = eb2[w * 16 + l15];

    const int NT = 8;  // 64-row tiles per block; 512 blocks x 8 = 4096 tiles
    const int t0 = blockIdx.x * NT;

    {
        const float* src = obs + ((size_t)t0 * 64 + srow) * 128 + sln * 16;
#pragma unroll
        for (int ii = 0; ii < 2; ++ii) {
            float4 v0 = *(const float4*)(src + ii * 8);
            float4 v1 = *(const float4*)(src + ii * 8 + 4);
            *(short8*)(xtA + srow * 128 + ((sln * 16 + ii * 8) ^ ssw)) = pack8(v0, v1);
        }
    }
    __syncthreads();

    for (int i = 0; i < NT; ++i) {
        const int tile = t0 + i;
        short* bufO = (i & 1) ? xtB : xtA;
        short* bufN = (i & 1) ? xtA : xtB;

        float4 pf[4];
        {
            const int tn = (i + 1 < NT) ? tile + 1 : tile;
            const float* src = obs + ((size_t)tn * 64 + srow) * 128 + sln * 16;
#pragma unroll
            for (int ii = 0; ii < 4; ++ii) pf[ii] = *(const float4*)(src + ii * 4);
        }

        // G1: obs -> x1 (tanh)
#pragma unroll
        for (int mf = 0; mf < 4; ++mf) {
            const int ra = mf * 16 + l15, swa = (ra & 7) << 3;
            short8 a[4];
#pragma unroll
            for (int kk = 0; kk < 4; ++kk)
                a[kk] = *(const short8*)&bufO[ra * 128 + ((kk * 32 + 8 * kg) ^ swa)];
            f32x4 acc = {bb1, bb1, bb1, bb1};
#pragma unroll
            for (int kk = 0; kk < 4; ++kk) acc = MFMA16(a[kk], fw1[kk], acc);
#pragma unroll
            for (int j = 0; j < 4; ++j) {
                int rw = mf * 16 + kg * 4 + j;
                xtC[rw * 128 + ((w * 16 + l15) ^ ((rw & 7) << 3))] = f2bf(ftanh(acc[j]));
            }
        }
        __syncthreads();

        // G2: x1 -> x2 (tanh), direct global stores in lstm layout; also write obsN
        const int t = (tile * 64) >> 10;
        const int b_base = (tile * 64) & 1023;
#pragma unroll
        for (int mf = 0; mf < 4; ++mf) {
            const int ra = mf * 16 + l15, swa = (ra & 7) << 3;
            short8 a[4];
#pragma unroll
            for (int kk = 0; kk < 4; ++kk)
                a[kk] = *(const short8*)&xtC[ra * 128 + ((kk * 32 + 8 * kg) ^ swa)];
            f32x4 acc = {bb2, bb2, bb2, bb2};
#pragma unroll
            for (int kk = 0; kk < 4; ++kk) acc = MFMA16(a[kk], fw2[kk], acc);
#pragma unroll
            for (int j = 0; j < 4; ++j) {
                int b = b_base + mf * 16 + kg * 4 + j;
                size_t idx = (((size_t)t * 256 + (b >> 2)) * 4 + (b & 3)) * 128 + w * 16 + l15;
                x2p[idx] = f2bf(ftanh(acc[j]));
            }
        }
#pragma unroll
        for (int ii = 0; ii < 2; ++ii) {
            *(short8*)(bufN + srow * 128 + ((sln * 16 + ii * 8) ^ ssw)) =
                pack8(pf[ii * 2], pf[ii * 2 + 1]);
        }
        __syncthreads();
    }
}

// ---------------- R: LSTM + fused heads + fused logprob epilogue ----------------
// 4 rows/WG, 8 waves, 256 WGs. h-A rows quad-replicated (batch = row>>2) so all 4 C-regs
// of lane (kg,l15) hold batch kg. xg kept in f32 regs; xgC[s] fed as MFMA C-in. Per-step
// x2b frag reads (R7 showed group-caching them regresses: reads are latency-hidden).
// Unmasked h2 in a 16-slot LDS ring; every 8th step all 8 waves each compute one past
// timestep's 9-dim head into LDS hd (48KB). Post-scan: in-WG logprob epilogue (HW log/exp).
__global__ __launch_bounds__(512) void lstm_kernel(
    const short* __restrict__ x2p, const float* __restrict__ whh,
    const float* __restrict__ wih,
    const float* __restrict__ h0, const float* __restrict__ c0,
    const float* __restrict__ bhh, const float* __restrict__ bih,
    const float* __restrict__ dones,
    const float* __restrict__ amw, const float* __restrict__ crw,
    const float* __restrict__ amb, const float* __restrict__ crb,
    const float* __restrict__ lstd, const float* __restrict__ actions,
    float* __restrict__ out)
{
    __shared__ __align__(16) short hbuf[2][4 * 160];   // masked h dbuf (MFMA A source)
    __shared__ __align__(16) short hring[16 * 640];    // unmasked h2 ring [slot][4*160]
    __shared__ __align__(16) short x2b[2][16 * 160];   // x2 group slots (XOR-swizzled)
    __shared__ float dlds[1028];                       // masks [t][j]
    __shared__ float hd[1024 * 12];                    // head results [t*4+kg][12] f32 (48KB)
    const int tid = threadIdx.x;
    const int l = tid & 63, w = tid >> 6;
    const int l15 = l & 15, kg = l >> 4;
    const int b0 = blockIdx.x * 4;
    const int d = w * 16 + l15;
    const int blk = blockIdx.x;
    const int xsw = (l15 & 7) << 3;                    // x2b read-side XOR swizzle

    // persistent w_hh + w_ih B-frags, converted in-reg from f32 (+ anti-remat pin)
    short8 bfr[4][4], bfi[4][4];
#pragma unroll
    for (int s = 0; s < 4; ++s)
#pragma unroll
        for (int kk = 0; kk < 4; ++kk) {
            const float* sr = whh + ((s * 128 + d) * 128 + kk * 32 + 8 * kg);
            const float* si = wih + ((s * 128 + d) * 128 + kk * 32 + 8 * kg);
            bfr[s][kk] = pack8(*(const float4*)sr, *(const float4*)(sr + 4));
            bfi[s][kk] = pack8(*(const float4*)si, *(const float4*)(si + 4));
            asm volatile("" : "+v"(bfr[s][kk]), "+v"(bfi[s][kk]));
        }

    // head B-frags: row l15: 0 = cr_w, 1..8 = am_w[l15-1], 9..15 = 0
    short8 hb4[4];
#pragma unroll
    for (int kk = 0; kk < 4; ++kk) {
        if (l15 == 0) {
            const float* s0 = crw + kk * 32 + 8 * kg;
            hb4[kk] = pack8(*(const float4*)s0, *(const float4*)(s0 + 4));
        } else if (l15 <= 8) {
            const float* s0 = amw + (l15 - 1) * 128 + kk * 32 + 8 * kg;
            hb4[kk] = pack8(*(const float4*)s0, *(const float4*)(s0 + 4));
        } else {
            hb4[kk] = short8{0, 0, 0, 0, 0, 0, 0, 0};
        }
        asm volatile("" : "+v"(hb4[kk]));
    }
    const float biasH = (l15 == 0) ? crb[0] : (l15 <= 8 ? amb[l15 - 1] : 0.f);

    for (int i = tid; i < 1028; i += 512) {
        int t = i >> 2, jj = i & 3;
        dlds[i] = (t < 256) ? 1.f - dones[t * 1024 + b0 + jj] : 1.f;
    }

    float bh[4];
#pragma unroll
    for (int s = 0; s < 4; ++s) bh[s] = bhh[s * 128 + d] + bih[s * 128 + d];

    // x2 staging: thread tid owns 8B: t_off=tid>>7, j=(tid>>5)&3, dim=(tid&31)*4
    const int st_toff = tid >> 7, st_j = (tid >> 5) & 3, st_dim = (tid & 31) * 4;
    const int st_row = st_j * 4 + st_toff;
    const int xrow160 = st_row * 160 + (st_dim ^ ((st_row & 7) << 3));  // swizzled write addr
#define X2GIDX(G) ((((size_t)(((G) * 4 + st_toff) <= 255 ? ((G) * 4 + st_toff) : 255) * 256 + blk) * 4 + st_j) * 128 + st_dim)

    // prologue: stage g0 -> x2b[0], g1 -> x2b[1]; issue g2 -> xpf
    {
        s16x4 v0 = *(const s16x4*)(x2p + X2GIDX(0));
        s16x4 v1 = *(const s16x4*)(x2p + X2GIDX(1));
        *(s16x4*)&x2b[0][xrow160] = v0;
        *(s16x4*)&x2b[1][xrow160] = v1;
    }
    s16x4 xpf = *(const s16x4*)(x2p + X2GIDX(2));
    asm volatile("s_waitcnt lgkmcnt(0)" ::: "memory");
    __syncthreads();

    // prologue x-chains for g0 (from x2b[0]) -> xgA, bh folded into C-init
    f32x4 xgA[4], xgB[4];
#pragma unroll
    for (int s = 0; s < 4; ++s) {
        short8 ax[4];
#pragma unroll
        for (int kk = 0; kk < 4; ++kk)
            ax[kk] = *(const short8*)&x2b[0][l15 * 160 + ((kk * 32 + kg * 8) ^ xsw)];
        f32x4 accX = {bh[s], bh[s], bh[s], bh[s]};
#pragma unroll
        for (int kk = 0; kk < 4; ++kk) accX = MFMA16(ax[kk], bfi[s][kk], accX);
        xgA[s] = accX;
    }

    float h = h0[(b0 + kg) * 128 + d];
    float c = c0[(b0 + kg) * 128 + d];
    hbuf[0][kg * 160 + d] = f2bf(h * dlds[kg]);
    asm volatile("s_waitcnt lgkmcnt(0)" ::: "memory");
    __syncthreads();

    const int aoff = (l15 >> 2) * 160;  // quad-replicated A rows: batch = row>>2
    float mreg = dlds[kg];

    // one LSTM step; DO_HEAD: all 8 waves each do one past step's head (t-8+w) into hd LDS
#define LSTM_STEP(t, hb, i_s, xgC, xgN, x2R, DO_T3, GNEXT, DO_HEAD)                        \
    {                                                                                      \
        short8 a[4];                                                                       \
        _Pragma("unroll")                                                                  \
        for (int kk = 0; kk < 4; ++kk)                                                     \
            a[kk] = *(const short8*)&hbuf[hb][aoff + kk * 32 + kg * 8];                    \
        f32x4 acc[4];                                                                      \
        _Pragma("unroll")                                                                  \
        for (int s = 0; s < 4; ++s) acc[s] = xgC[s];                                       \
        _Pragma("unroll")                                                                  \
        for (int kk = 0; kk < 4; ++kk)                                                     \
            _Pragma("unroll")                                                              \
            for (int s = 0; s < 4; ++s) acc[s] = MFMA16(a[kk], bfr[s][kk], acc[s]);        \
        { /* x-chain: gate i_s of next group, full M=16, bh folded into C-init */          \
            short8 ax[4];                                                                  \
            _Pragma("unroll")                                                              \
            for (int kk = 0; kk < 4; ++kk)                                                 \
                ax[kk] = *(const short8*)&x2R[l15 * 160 + ((kk * 32 + kg * 8) ^ xsw)];     \
            f32x4 accX = {bh[i_s], bh[i_s], bh[i_s], bh[i_s]};                             \
            _Pragma("unroll")                                                              \
            for (int kk = 0; kk < 4; ++kk) accX = MFMA16(ax[kk], bfi[i_s][kk], accX);      \
            xgN[i_s] = accX;                                                               \
        }                                                                                  \
        if (DO_HEAD) { /* head for step th = t-8+w, from ring slot th&15 */                \
            int th = (t) - 8 + w;                                                          \
            const short* hr = &hring[(th & 15) * 640];                                     \
            short8 ah[4];                                                                  \
            _Pragma("unroll")                                                              \
            for (int kk = 0; kk < 4; ++kk)                                                 \
                ah[kk] = *(const short8*)&hr[aoff + kk * 32 + kg * 8];                     \
            f32x4 aH = {biasH, biasH, biasH, biasH};                                       \
            _Pragma("unroll")                                                              \
            for (int kk = 0; kk < 4; ++kk) aH = MFMA16(ah[kk], hb4[kk], aH);               \
            if (l15 < 9) hd[((th) * 4 + kg) * 12 + l15] = aH[0];                           \
        }                                                                                  \
        if (DO_T3) {                                                                      \
            *(s16x4*)&x2W[xrow160] = xpf;                                                  \
            xpf = *(const s16x4*)(x2p + X2GIDX(GNEXT));                                    \
        }                                                                                  \
        float mn = dlds[((t) + 1) * 4 + kg];                                               \
        float gi = acc[0][i_s];                                                            \
        float gf = acc[1][i_s];                                                            \
        float gg = acc[2][i_s];                                                            \
        float go = acc[3][i_s];                                                            \
        c = fsigm(gf) * (c * mreg) + fsigm(gi) * ftanh(gg);                                \
        float h2 = fsigm(go) * ftanh(c);                                                   \
        h = h2;                                                                            \
        mreg = mn;                                                                         \
        hbuf[(hb) ^ 1][kg * 160 + d] = f2bf(h2 * mn);                                      \
        hring[((t) & 15) * 640 + kg * 160 + d] = f2bf(h2);                                 \
        asm volatile("s_waitcnt lgkmcnt(0)" ::: "memory");                                 \
        __builtin_amdgcn_s_barrier();                                                      \
        asm volatile("" ::: "memory");                                                     \
    }

    for (int g = 0; g < 64; g += 2) {
        {   // even group g: consume xgA, produce xgB from x2b[1] (group g+1)
            const int tb = g * 4;
            const short* x2R = &x2b[1][0];
            short* x2W = &x2b[0][0];   // at t3: stage group g+2 into slot 0
            LSTM_STEP(tb + 0, 0, 0, xgA, xgB, x2R, 0, 0, (g > 0));
            LSTM_STEP(tb + 1, 1, 1, xgA, xgB, x2R, 0, 0, 0);
            LSTM_STEP(tb + 2, 0, 2, xgA, xgB, x2R, 0, 0, 0);
            LSTM_STEP(tb + 3, 1, 3, xgA, xgB, x2R, 1, (g + 3), 0);
        }
        {   // odd group g+1: consume xgB, produce xgA from x2b[0] (group g+2)
            const int tb = (g + 1) * 4;
            const short* x2R = &x2b[0][0];
            short* x2W = &x2b[1][0];   // at t3: stage group g+3 into slot 1
            LSTM_STEP(tb + 0, 0, 0, xgB, xgA, x2R, 0, 0, 0);
            LSTM_STEP(tb + 1, 1, 1, xgB, xgA, x2R, 0, 0, 0);
            LSTM_STEP(tb + 2, 0, 2, xgB, xgA, x2R, 0, 0, 0);
            LSTM_STEP(tb + 3, 1, 3, xgB, xgA, x2R, 1, (g + 4), 0);
        }
    }
#undef LSTM_STEP
#undef X2GIDX

    // final heads for t = 248..255 (ring slots 8..15), all 8 waves, one step each
    {
        int th = 248 + w;
        const short* hr = &hring[(th & 15) * 640];
        short8 ah[4];
#pragma unroll
        for (int kk = 0; kk < 4; ++kk)
            ah[kk] = *(const short8*)&hr[aoff + kk * 32 + kg * 8];
        f32x4 aH = {biasH, biasH, biasH, biasH};
#pragma unroll
        for (int kk = 0; kk < 4; ++kk) aH = MFMA16(ah[kk], hb4[kk], aH);
        if (l15 < 9) hd[(th * 4 + kg) * 12 + l15] = aH[0];
    }

    out[3 * TB_ + (b0 + kg) * 128 + d] = h;
    out[3 * TB_ + BH_ + (b0 + kg) * 128 + d] = c;

    // ---- fused logprob/entropy/value epilogue (HW v_log_f32 / v_exp_f32) ----
    __syncthreads();
    for (int rr = tid; rr < 1024; rr += 512) {
        const int t = rr >> 2, bb = rr & 3;
        const float* hp = &hd[rr * 12];
        const float* ap = actions + ((size_t)t * 1024 + b0 + bb) * 8;
        float4 a0 = *(const float4*)(ap);
        float4 a1 = *(const float4*)(ap + 4);
        float act[8] = {a0.x, a0.y, a0.z, a0.w, a1.x, a1.y, a1.z, a1.w};
        float lp = 0.f, lj = 0.f, entS = 0.f;
#pragma unroll
        for (int ai = 0; ai < 8; ++ai) {
            float x = act[ai];
            float xc = fminf(fmaxf(x, -1.f + 1e-6f), 1.f - 1e-6f);
            float u = 0.5f * LN2_F *
                      (__builtin_amdgcn_logf(1.f + xc) - __builtin_amdgcn_logf(1.f - xc));
            float ls = lstd[ai];
            float z = (u - hp[1 + ai]) * fexp(-ls);
            lp += -0.5f * z * z - ls;
            lj += LN2_F * __builtin_amdgcn_logf(1.f - x * x + 1e-6f);
            entS += ls;
        }
        lp -= 8.f * 0.5f * LOG2PI_F;
        entS += 8.f * (0.5f + 0.5f * LOG2PI_F);
        const int r = t * 1024 + b0 + bb;
        out[r] = lp - lj;
        out[TB_ + r] = entS + lj;
        out[2 * TB_ + r] = hp[0];
    }
}

extern "C" void kernel_launch(void* const* d_in, const int* in_sizes, int n_in,
                              void* d_out, int out_size, void* d_ws, size_t ws_size,
                              hipStream_t stream) {
    const float* obs   = (const float*)d_in[0];
    const float* acts  = (const float*)d_in[1];
    const float* dones = (const float*)d_in[2];
    const float* h0    = (const float*)d_in[3];
    const float* c0    = (const float*)d_in[4];
    const float* w1    = (const float*)d_in[5];
    const float* b1    = (const float*)d_in[6];
    const float* w2    = (const float*)d_in[7];
    const float* b2    = (const float*)d_in[8];
    const float* wih   = (const float*)d_in[9];
    const float* whh   = (const float*)d_in[10];
    const float* bih   = (const float*)d_in[11];
    const float* bhh   = (const float*)d_in[12];
    const float* amw   = (const float*)d_in[13];
    const float* amb   = (const float*)d_in[14];
    const float* lstd  = (const float*)d_in[15];
    const float* crw   = (const float*)d_in[16];
    const float* crb   = (const float*)d_in[17];
    float* out = (float*)d_out;

    short* x2p = (short*)d_ws;               // 64 MB  [t][blk][j][dim] bf16
    if (ws_size < (size_t)67108864) return;

    hipLaunchKernelGGL(ex_kernel, dim3(512), dim3(512), 0, stream,
                       obs, b1, b2, w1, w2, x2p);
    hipLaunchKernelGGL(lstm_kernel, dim3(256), dim3(512), 0, stream,
                       x2p, whh, wih, h0, c0, bhh, bih, dones,
                       amw, crw, amb, crb, lstd, acts, out);
}